// Round 9
// baseline (25.831 us; speedup 1.0000x reference)
//
#include <hip/hip_runtime.h>
#include <hip/hip_bf16.h>

// IPN layer: per batch b, X = x[b] (64 rows x 32 cols, fp32).
// out[b, p] = dot(X[i], X[j]) for row-major strict-upper pairs (i<j), packed.
// B=8192, F=64, E=32, PAIRS = 2016.
//
// MFMA formulation: gram tile (p,q) = mfma_f32_16x16x32_bf16(frag[p], frag[q]);
// the same lane-fragment serves as both A and B for X·X^T.
//
// R9: phase-overlap pipeline. Two batches per wave; batch1's global loads are
// issued BEFORE batch0's epilogue and pinned with sched_barrier(0) so they
// stay in flight under batch0's NT store stream (chip-wide read/write
// overlap). Conversion via __float2bfloat16 (compiler emits v_cvt_pk).
// Epilogue: 4-pass over a 1024-float wave-private LDS chunk buffer
// (16 KiB/block), NT f32x4 stream-out. No barriers anywhere.

#define FDIM 64
#define EDIM 32
#define PAIRS 2016

typedef __attribute__((ext_vector_type(8))) short bf16x8;
typedef __attribute__((ext_vector_type(4))) float f32x4;

static __device__ __forceinline__ short f2bf(float f) {
    __hip_bfloat16 h = __float2bfloat16(f);   // RNE; compiler packs to v_cvt_pk_bf16_f32
    union { __hip_bfloat16 h; short s; } u; u.h = h;
    return u.s;
}

static __device__ __forceinline__ void cvt_frags(const f32x4 raw[8], bf16x8 frag[4]) {
    #pragma unroll
    for (int p = 0; p < 4; ++p) {
        bf16x8 f;
        f[0] = f2bf(raw[2*p].x); f[1] = f2bf(raw[2*p].y);
        f[2] = f2bf(raw[2*p].z); f[3] = f2bf(raw[2*p].w);
        f[4] = f2bf(raw[2*p+1].x); f[5] = f2bf(raw[2*p+1].y);
        f[6] = f2bf(raw[2*p+1].z); f[7] = f2bf(raw[2*p+1].w);
        frag[p] = f;
    }
}

static __device__ __forceinline__ void load_raw(const float* __restrict__ xb,
                                                int r16, int kb, f32x4 raw[8]) {
    #pragma unroll
    for (int p = 0; p < 4; ++p) {
        const float* rp = xb + (p * 16 + r16) * EDIM + kb;
        raw[2*p]   = *(const f32x4*)(rp);
        raw[2*p+1] = *(const f32x4*)(rp + 4);
    }
}

static __device__ __forceinline__ void epilogue(const bf16x8 frag[4],
                                                float* __restrict__ pb,
                                                float* __restrict__ ob, int l) {
    f32x4 acc[10];
    #pragma unroll
    for (int t = 0; t < 10; ++t) acc[t] = (f32x4)(0.0f);
    {
        int idx = 0;
        #pragma unroll
        for (int p = 0; p < 4; ++p)
            #pragma unroll
            for (int q = p; q < 4; ++q) {
                acc[idx] = __builtin_amdgcn_mfma_f32_16x16x32_bf16(
                    frag[p], frag[q], acc[idx], 0, 0, 0);
                ++idx;
            }
    }

    // 4-pass: scatter row-block p's packed chunk into LDS, NT-stream it.
    // C/D layout: col = lane&15, row = (lane>>4)*4 + reg   [m89]
    // packed pos(i,j) = i*(127-i)/2 + (j - i - 1); chunk base = off(16p)
    const int jc = l & 15;
    const int ir = (l >> 4) * 4;
    const int base_p[4] = {0, 888, 1520, 1896};
    const int n4_p[4]   = {222, 158, 94, 30};
    {
        int idx = 0;
        #pragma unroll
        for (int p = 0; p < 4; ++p) {
            #pragma unroll
            for (int q = p; q < 4; ++q) {
                const int jg = q * 16 + jc;
                #pragma unroll
                for (int t = 0; t < 4; ++t) {
                    const int ig = p * 16 + ir + t;
                    if (p < q || jg > ig) {
                        const int pos = ig * (2 * FDIM - 1 - ig) / 2 - ig - 1
                                        + jg - base_p[p];
                        pb[pos] = acc[idx][t];
                    }
                }
                ++idx;
            }
            const f32x4* pb4 = (const f32x4*)pb;
            f32x4* ob4 = (f32x4*)(ob + base_p[p]);
            #pragma unroll
            for (int it = 0; it * 64 < n4_p[p]; ++it) {
                const int idx4 = it * 64 + l;
                if (idx4 < n4_p[p]) {
                    f32x4 v = pb4[idx4];
                    __builtin_nontemporal_store(v, ob4 + idx4);
                }
            }
        }
    }
}

__global__ __launch_bounds__(256, 4) void ipn_mfma_kernel(const float* __restrict__ x,
                                                          float* __restrict__ out) {
    __shared__ float pbuf[4][1024];    // 4 waves * 4 KiB chunk staging

    const int tid = threadIdx.x;
    const int w   = tid >> 6;
    const int l   = tid & 63;
    const int wid = blockIdx.x * 4 + w;
    const int b0  = wid * 2;
    const int b1  = b0 + 1;

    const int r16 = l & 15;
    const int kb  = (l >> 4) * 8;

    float* pb = pbuf[w];

    // batch 0 loads + convert
    f32x4 raw0[8];
    load_raw(x + (size_t)b0 * (FDIM * EDIM), r16, kb, raw0);
    bf16x8 frag0[4];
    cvt_frags(raw0, frag0);

    // batch 1 loads issued NOW, pinned above the batch-0 epilogue:
    f32x4 raw1[8];
    load_raw(x + (size_t)b1 * (FDIM * EDIM), r16, kb, raw1);
    __builtin_amdgcn_sched_barrier(0);   // keep raw1 loads in flight under b0 stores

    epilogue(frag0, pb, out + (size_t)b0 * PAIRS, l);

    bf16x8 frag1[4];
    cvt_frags(raw1, frag1);
    epilogue(frag1, pb, out + (size_t)b1 * PAIRS, l);
}

extern "C" void kernel_launch(void* const* d_in, const int* in_sizes, int n_in,
                              void* d_out, int out_size, void* d_ws, size_t ws_size,
                              hipStream_t stream) {
    const float* x = (const float*)d_in[0];
    float* out = (float*)d_out;
    const int nb = in_sizes[0] / (FDIM * EDIM);   // 8192 batches
    const int grid = nb / 8;                      // 4 waves/block, 2 batches/wave
    ipn_mfma_kernel<<<grid, 256, 0, stream>>>(x, out);
}

// Round 10
// 25.304 us; speedup vs baseline: 1.0208x; 1.0208x over previous
//
#include <hip/hip_runtime.h>

// IPN layer: per batch b, X = x[b] (64 rows x 32 cols, fp32).
// out[b, p] = dot(X[i], X[j]) for row-major strict-upper pairs (i<j), packed.
// B=8192, F=64, E=32, PAIRS = 2016.
//
// FINAL (best-measured, R5 = 25.25 us): MFMA gram formulation — tile (p,q) =
// mfma_f32_16x16x32_bf16(frag[p], frag[q]); for X·X^T the same lane-fragment
// serves as both A and B operands. One wave per TWO batches (loads issued up
// front); wave-private LDS staging of the packed strict-upper output, then
// dense aligned f32x4 NONTEMPORAL stream-out (keeps the 64MB input
// L3-resident across replays; A/B: NT 25.30 vs cache-routed 26.06).
//
// Plateau evidence (R4-R9): occupancy x2, enforced read/write overlap, store
// flavor, batch pipelining all neutral within +/-3%. Model: 130 MB logical
// traffic / 6.29 TB/s copy ceiling = 20.7 us + ~5 us replay overhead = ~25.5,
// matching all variants => practical mixed-stream roofline.

#define FDIM 64
#define EDIM 32
#define PAIRS 2016

typedef __attribute__((ext_vector_type(8))) short bf16x8;
typedef __attribute__((ext_vector_type(4))) float f32x4;

static __device__ __forceinline__ short f2bf(float f) {
    union { float f; unsigned u; } v; v.f = f;
    unsigned r = v.u + 0x7FFFu + ((v.u >> 16) & 1u);   // RNE truncate to bf16
    return (short)(r >> 16);
}

static __device__ __forceinline__ void load_frags(const float* __restrict__ xb,
                                                  int r16, int kb, bf16x8 frag[4]) {
    #pragma unroll
    for (int p = 0; p < 4; ++p) {
        const float* rp = xb + (p * 16 + r16) * EDIM + kb;
        f32x4 lo = *(const f32x4*)(rp);
        f32x4 hi = *(const f32x4*)(rp + 4);
        bf16x8 f;
        f[0] = f2bf(lo.x); f[1] = f2bf(lo.y); f[2] = f2bf(lo.z); f[3] = f2bf(lo.w);
        f[4] = f2bf(hi.x); f[5] = f2bf(hi.y); f[6] = f2bf(hi.z); f[7] = f2bf(hi.w);
        frag[p] = f;
    }
}

static __device__ __forceinline__ void compute_store(const bf16x8 frag[4],
                                                     float* __restrict__ pb,
                                                     float* __restrict__ ob,
                                                     int l) {
    f32x4 acc[10];
    #pragma unroll
    for (int t = 0; t < 10; ++t) acc[t] = (f32x4)(0.0f);
    {
        int idx = 0;
        #pragma unroll
        for (int p = 0; p < 4; ++p)
            #pragma unroll
            for (int q = p; q < 4; ++q) {
                acc[idx] = __builtin_amdgcn_mfma_f32_16x16x32_bf16(
                    frag[p], frag[q], acc[idx], 0, 0, 0);
                ++idx;
            }
    }

    // scatter packed values into wave-private LDS
    // C/D layout: col = lane&15, row = (lane>>4)*4 + reg   [m89]
    const int jc = l & 15;
    const int ir = (l >> 4) * 4;
    {
        int idx = 0;
        #pragma unroll
        for (int p = 0; p < 4; ++p)
            #pragma unroll
            for (int q = p; q < 4; ++q) {
                const int jg = q * 16 + jc;
                #pragma unroll
                for (int t = 0; t < 4; ++t) {
                    const int ig = p * 16 + ir + t;
                    if (p < q || jg > ig) {
                        const int base = ig * (2 * FDIM - 1 - ig) / 2 - ig - 1;
                        pb[base + jg] = acc[idx][t];
                    }
                }
                ++idx;
            }
    }
    // wave-private producer/consumer: compiler's lgkmcnt ordering, no barrier

    // dense nontemporal f32x4 stream-out (504 float4 per batch)
    const f32x4* pb4 = (const f32x4*)pb;
    f32x4* ob4 = (f32x4*)ob;
    #pragma unroll
    for (int it = 0; it < 8; ++it) {
        const int idx4 = it * 64 + l;
        if (idx4 < 504) {
            f32x4 v = pb4[idx4];
            __builtin_nontemporal_store(v, ob4 + idx4);
        }
    }
}

__global__ __launch_bounds__(256, 4) void ipn_mfma_kernel(const float* __restrict__ x,
                                                          float* __restrict__ out) {
    __shared__ float pbuf[4][2048];    // 4 waves * 8 KiB packed-output staging

    const int tid = threadIdx.x;
    const int w   = tid >> 6;          // wave in block
    const int l   = tid & 63;          // lane
    const int bw  = blockIdx.x * 4 + w;
    const int b0  = bw * 2;            // this wave's two batches
    const int b1  = b0 + 1;

    const int r16 = l & 15;
    const int kb  = (l >> 4) * 8;

    // issue BOTH batches' loads up front (independent -> compiler hoists)
    bf16x8 frag0[4], frag1[4];
    load_frags(x + (size_t)b0 * (FDIM * EDIM), r16, kb, frag0);
    load_frags(x + (size_t)b1 * (FDIM * EDIM), r16, kb, frag1);

    float* pb = pbuf[w];
    compute_store(frag0, pb, out + (size_t)b0 * PAIRS, l);
    compute_store(frag1, pb, out + (size_t)b1 * PAIRS, l);
}

extern "C" void kernel_launch(void* const* d_in, const int* in_sizes, int n_in,
                              void* d_out, int out_size, void* d_ws, size_t ws_size,
                              hipStream_t stream) {
    const float* x = (const float*)d_in[0];
    float* out = (float*)d_out;
    const int nb = in_sizes[0] / (FDIM * EDIM);   // 8192 batches
    const int grid = nb / 8;                      // 4 waves/block * 2 batches/wave
    ipn_mfma_kernel<<<grid, 256, 0, stream>>>(x, out);
}